// Round 14
// baseline (269.281 us; speedup 1.0000x reference)
//
#include <hip/hip_runtime.h>
#include <math.h>

// PropagatorBlock: B=512, H=1024, K=256, V=512, MUL=4
constexpr int B_ = 512;
constexpr int H_ = 1024;
constexpr int K_ = 256;
constexpr int V_ = 512;
constexpr int F_ = 4096;  // MUL*H

typedef __attribute__((ext_vector_type(8))) short bf16x8;
typedef __attribute__((ext_vector_type(4))) float f32x4;

#define GLD16(gp, lp)                                                   \
  __builtin_amdgcn_global_load_lds(                                     \
      (const __attribute__((address_space(1))) void*)(gp),              \
      (__attribute__((address_space(3))) void*)(lp), 16, 0, 0)

// ---- helpers ----------------------------------------------------------
static __device__ __forceinline__ unsigned short f2bf(float f) {
  union { float f; unsigned int u; } a; a.f = f;
  unsigned int u = a.u;
  return (unsigned short)((u + 0x7FFFu + ((u >> 16) & 1u)) >> 16);  // RNE
}

static __device__ __forceinline__ float block_sum256(float v, float* sbuf) {
#pragma unroll
  for (int o = 32; o > 0; o >>= 1) v += __shfl_down(v, o, 64);
  const int w = threadIdx.x >> 6;
  __syncthreads();
  if ((threadIdx.x & 63) == 0) sbuf[w] = v;
  __syncthreads();
  return sbuf[0] + sbuf[1] + sbuf[2] + sbuf[3];
}

// 512-thread block sum (8 waves)
static __device__ __forceinline__ float block_sum512(float v, float* sbuf) {
#pragma unroll
  for (int o = 32; o > 0; o >>= 1) v += __shfl_down(v, o, 64);
  const int w = threadIdx.x >> 6;
  __syncthreads();
  if ((threadIdx.x & 63) == 0) sbuf[w] = v;
  __syncthreads();
  float s = 0.f;
#pragma unroll
  for (int i = 0; i < 8; ++i) s += sbuf[i];
  return s;
}

// ---- prep v2: all 6 weight transposes (64x64 tiles) + norm1 -----------
struct TJob { const float* src; unsigned short* dst; int R, C, cb, blk0; };
struct TArgs { TJob j[6]; };

__global__ __launch_bounds__(256) void prep_kernel(
    TArgs args, const float* __restrict__ x, const float* __restrict__ scale,
    unsigned short* __restrict__ h1, int tblocks) {
  __shared__ unsigned short t16[64][68];
  __shared__ float sbuf[4];
  const int id = blockIdx.x;
  const int tid = threadIdx.x;
  if (id >= tblocks) {
    const int b = id - tblocks;
    const float* xr = x + ((size_t)b << 10);
    float loc[4]; float ss = 0.f;
#pragma unroll
    for (int it = 0; it < 4; ++it) { float v = xr[(it << 8) + tid]; loc[it] = v; ss += v * v; }
    ss = block_sum256(ss, sbuf);
    const float r = rsqrtf(ss * (1.f / 1024.f) + 1e-6f);
    unsigned short* orow = h1 + ((size_t)b << 10);
#pragma unroll
    for (int it = 0; it < 4; ++it) { const int j = (it << 8) + tid; orow[j] = f2bf(loc[it] * r * scale[j]); }
    return;
  }
  int ji = 0;
#pragma unroll
  for (int i = 1; i < 6; ++i) if (id >= args.j[i].blk0) ji = i;
  const TJob J = args.j[ji];
  const int lb = id - J.blk0;
  const int bx = lb % J.cb, by = lb / J.cb;
  const int c0 = bx << 6, r0 = by << 6;
  const int lr = tid >> 4, lc = (tid & 15) << 2;
#pragma unroll
  for (int i = 0; i < 4; ++i) {
    const int row = (i << 4) + lr;
    const f32x4 v = *(const f32x4*)&J.src[(size_t)(r0 + row) * J.C + c0 + lc];
    ushort4 u;
    u.x = f2bf(v.x); u.y = f2bf(v.y); u.z = f2bf(v.z); u.w = f2bf(v.w);
    *(ushort4*)&t16[row][lc] = u;
  }
  __syncthreads();
  const int oc = tid >> 5, j = tid & 31;
#pragma unroll
  for (int i = 0; i < 8; ++i) {
    const int c = (i << 3) + oc;
    const unsigned lo = t16[2 * j][c], hi = t16[2 * j + 1][c];
    *(unsigned*)&J.dst[(size_t)(c0 + c) * J.R + r0 + 2 * j] = lo | (hi << 16);
  }
}

// ---- GEMM: C[M][N] (+z partials) = A[M][K] * BT[N][K]^T ---------------
// 2-phase dbuf + counted vmcnt (tile t+1 loads stay in flight).
template <int BN, bool SILU>
__global__ __launch_bounds__(256) void gemm2(
    const unsigned short* __restrict__ A, const unsigned short* __restrict__ BT,
    float* __restrict__ Cf, unsigned short* __restrict__ Cb,
    const float* __restrict__ bias, int M, int N, int K, int Ksub) {
  __shared__ unsigned short lsa[2][64 * 64];
  __shared__ unsigned short lsb[2][BN * 64];
  const int tid = threadIdx.x;
  const int m0 = blockIdx.y << 6, n0 = blockIdx.x * BN;
  const int kbeg = blockIdx.z * Ksub;
  const int w = tid >> 6, l = tid & 63;
  const int l15 = l & 15, lg = l >> 4;
  const int wm = (w >> 1) * 32, wn = (w & 1) * (BN / 2);
  constexpr int NF = BN / 32;
  f32x4 acc[2][NF] = {};

  const int sr = l >> 3;
  const int sc = ((l & 7) ^ sr) * 8;
  const int srow = w * 8 + sr;
  const unsigned short* ga0 = A + (size_t)(m0 + srow) * K + sc;
  const unsigned short* gb0 = BT + (size_t)(n0 + srow) * K + sc;
  const int rx = l15 & 7;

  auto STAGE = [&](int buf, int k0) {
#pragma unroll
    for (int c = 0; c < 2; ++c)
      GLD16(ga0 + (size_t)(c * 32) * K + k0, &lsa[buf][c * 2048 + w * 512]);
#pragma unroll
    for (int c = 0; c < NF; ++c)
      GLD16(gb0 + (size_t)(c * 32) * K + k0, &lsb[buf][c * 2048 + w * 512]);
  };

  const int nt = Ksub >> 6;
  STAGE(0, kbeg);
  __builtin_amdgcn_sched_barrier(0);
  int cur = 0;
  for (int t = 0; t < nt; ++t) {
    if (t + 1 < nt) {
      STAGE(cur ^ 1, kbeg + ((t + 1) << 6));
      __builtin_amdgcn_sched_barrier(0);
      if constexpr (NF == 2) {
        asm volatile("s_waitcnt vmcnt(4)" ::: "memory");
      } else {
        asm volatile("s_waitcnt vmcnt(6)" ::: "memory");
      }
    } else {
      asm volatile("s_waitcnt vmcnt(0)" ::: "memory");
    }
    __builtin_amdgcn_sched_barrier(0);
    __builtin_amdgcn_s_barrier();
    __builtin_amdgcn_sched_barrier(0);
    const unsigned short* la = lsa[cur];
    const unsigned short* lb = lsb[cur];
    bf16x8 af[2][2], bv[2][NF];
#pragma unroll
    for (int kh = 0; kh < 2; ++kh) {
      const int ch = ((kh * 4 + lg) ^ rx) * 8;
#pragma unroll
      for (int mf = 0; mf < 2; ++mf)
        af[kh][mf] = *(const bf16x8*)&la[(wm + mf * 16 + l15) * 64 + ch];
#pragma unroll
      for (int nf = 0; nf < NF; ++nf)
        bv[kh][nf] = *(const bf16x8*)&lb[(wn + nf * 16 + l15) * 64 + ch];
    }
#pragma unroll
    for (int kh = 0; kh < 2; ++kh)
#pragma unroll
      for (int mf = 0; mf < 2; ++mf)
#pragma unroll
        for (int nf = 0; nf < NF; ++nf)
          acc[mf][nf] = __builtin_amdgcn_mfma_f32_16x16x32_bf16(
              af[kh][mf], bv[kh][nf], acc[mf][nf], 0, 0, 0);
    asm volatile("s_waitcnt lgkmcnt(0)" ::: "memory");
    __builtin_amdgcn_sched_barrier(0);
    __builtin_amdgcn_s_barrier();
    __builtin_amdgcn_sched_barrier(0);
    cur ^= 1;
  }

  if constexpr (SILU) {
#pragma unroll
    for (int mf = 0; mf < 2; ++mf)
#pragma unroll
      for (int nf = 0; nf < NF; ++nf) {
        const int col = n0 + wn + nf * 16 + l15;
        const float bi = bias[col];
#pragma unroll
        for (int i = 0; i < 4; ++i) {
          const int row = m0 + wm + mf * 16 + (lg << 2) + i;
          const float z = acc[mf][nf][i] + bi;
          Cb[(size_t)row * N + col] = f2bf(z / (1.f + expf(-z)));
        }
      }
  } else {
    float* Cz = Cf + (size_t)blockIdx.z * M * N;
#pragma unroll
    for (int mf = 0; mf < 2; ++mf)
#pragma unroll
      for (int nf = 0; nf < NF; ++nf) {
        const int r = m0 + wm + mf * 16 + (lg << 2);
        const int c = n0 + wn + nf * 16 + l15;
        float* cp = Cz + (size_t)r * N + c;
#pragma unroll
        for (int i = 0; i < 4; ++i) cp[(size_t)i * N] = acc[mf][nf][i];
      }
  }
}

// ---- einsum (R9 version): 512 thr / 8 waves, block=(b, v-half) --------
__global__ __launch_bounds__(512) void read_einsum(
    const float* __restrict__ mem, const float* __restrict__ rk_pre,
    unsigned short* __restrict__ rv) {
  __shared__ float sbuf[8];
  __shared__ float lrk[256];
  __shared__ float part[8][256];
  const int tid = threadIdx.x;
  const int b = blockIdx.x >> 1;
  const int v0 = (blockIdx.x & 1) << 8;  // 256 cols per block
  {
    constexpr size_t PS = (size_t)B_ * K_;
    float v = 0.f;
    if (tid < 256) {
#pragma unroll
      for (int z = 0; z < 4; ++z) v += rk_pre[z * PS + ((size_t)b << 8) + tid];
    }
    const float ss = block_sum512(v * v, sbuf);
    if (tid < 256) lrk[tid] = v * rsqrtf(ss * (1.f / 256.f) + 1e-6f) * 0.0625f;
  }
  __syncthreads();
  const int w = tid >> 6, l = tid & 63;
  const float* base = mem + ((size_t)b << 17) + v0 + (l << 2);
  f32x4 a = {0.f, 0.f, 0.f, 0.f};
#pragma unroll 8
  for (int kk = 0; kk < 32; ++kk) {
    const int k = (w << 5) + kk;
    const f32x4 m4 = *(const f32x4*)(base + ((size_t)k << 9));
    const float s = lrk[k];
    a.x += s * m4.x; a.y += s * m4.y; a.z += s * m4.z; a.w += s * m4.w;
  }
  *(f32x4*)&part[w][l << 2] = a;
  __syncthreads();
  if (tid < 256) {
    float s = 0.f;
#pragma unroll
    for (int g = 0; g < 8; ++g) s += part[g][tid];
    rv[((size_t)b << 9) + v0 + tid] = f2bf(s);
  }
}

// ---- x1 = x + gamma1*sum_z proj; h2 = bf16(rmsnorm(x1)*scale2) --------
__global__ __launch_bounds__(256) void add1_norm2(
    const float* __restrict__ x, const float* __restrict__ proj,
    const float* __restrict__ gamma1, const float* __restrict__ scale2,
    float* __restrict__ x1, unsigned short* __restrict__ h2) {
  __shared__ float sbuf[4];
  const int b = blockIdx.x, tid = threadIdx.x;
  const size_t ro = (size_t)b << 10;
  constexpr size_t PS = (size_t)B_ * H_;
  float loc[4]; float ss = 0.f;
#pragma unroll
  for (int it = 0; it < 4; ++it) {
    const int j = (it << 8) + tid;
    const float v = x[ro + j] + gamma1[j] * (proj[ro + j] + proj[PS + ro + j]);
    x1[ro + j] = v; loc[it] = v; ss += v * v;
  }
  ss = block_sum256(ss, sbuf);
  const float r = rsqrtf(ss * (1.f / 1024.f) + 1e-6f);
#pragma unroll
  for (int it = 0; it < 4; ++it) { const int j = (it << 8) + tid; h2[ro + j] = f2bf(loc[it] * r * scale2[j]); }
}

// ---- x2 = x1 + gamma2*(sum_z fc2p[z]+b2); w3; eta; forget -------------
__global__ __launch_bounds__(256) void add2_norm3(
    const float* __restrict__ x1, const float* __restrict__ fc2p,
    const float* __restrict__ gamma2, const float* __restrict__ bias2,
    const float* __restrict__ scale3, const float* __restrict__ wgate,
    const float* __restrict__ bgate, const float* __restrict__ wforget,
    const float* __restrict__ bforget, float* __restrict__ xout,
    unsigned short* __restrict__ w3, float* __restrict__ eta, float* __restrict__ fg) {
  __shared__ float sbuf[4];
  const int b = blockIdx.x, tid = threadIdx.x;
  const size_t ro = (size_t)b << 10;
  constexpr size_t PS = (size_t)B_ * H_;
  float loc[4]; float ss = 0.f;
#pragma unroll
  for (int it = 0; it < 4; ++it) {
    const int j = (it << 8) + tid;
    float acc = bias2[j];
#pragma unroll
    for (int z = 0; z < 4; ++z) acc += fc2p[z * PS + ro + j];
    const float v = x1[ro + j] + gamma2[j] * acc;
    xout[ro + j] = v; loc[it] = v; ss += v * v;
  }
  ss = block_sum256(ss, sbuf);
  const float r = rsqrtf(ss * (1.f / 1024.f) + 1e-6f);
  float dg = 0.f, df = 0.f;
#pragma unroll
  for (int it = 0; it < 4; ++it) {
    const int j = (it << 8) + tid;
    const float w = loc[it] * r * scale3[j];
    w3[ro + j] = f2bf(w);
    dg += w * wgate[j]; df += w * wforget[j];
  }
  dg = block_sum256(dg, sbuf);
  df = block_sum256(df, sbuf);
  if (tid == 0) {
    eta[b] = 0.1f / (1.f + expf(-(dg + bgate[0])));
    fg[b] = 0.02f / (1.f + expf(-(df + bforget[0])));
  }
}

// ---- write_update v8: v-eighth slab, 32 waves/CU, 8-deep reg slab -----
// block = (b, 64-col slab). Thread owns 8 rows x 1 quad (buf[8] = 32 VGPR)
// -> fits 64-VGPR budget -> 8 waves/EU. NT loads (mem dead after this).
__global__ __launch_bounds__(512, 8) void write_update(
    const float* __restrict__ mem, const float* __restrict__ wkvp,
    const float* __restrict__ eta, const float* __restrict__ fg,
    const unsigned char* __restrict__ valid, float* __restrict__ outm) {
  __shared__ float sbuf[8];
  __shared__ float lwk[256];
  __shared__ f32x4 part[32][16];
  __shared__ float lerr[64];
  const int tid = threadIdx.x;
  const int b = blockIdx.x >> 3;
  const int v0 = (blockIdx.x & 7) << 6;  // 64 cols per block
  constexpr size_t PS = (size_t)B_ * 768;
  {
    float v = 0.f;
    if (tid < 256) v = wkvp[(size_t)b * 768 + tid] + wkvp[PS + (size_t)b * 768 + tid];
    const float ss = block_sum512(v * v, sbuf);
    if (tid < 256) lwk[tid] = v * rsqrtf(ss * (1.f / 256.f) + 1e-6f) * 0.0625f;
  }
  __syncthreads();
  const int c4 = tid & 15;  // col quad (16 quads = 64 cols)
  const int g = tid >> 4;   // row group 0..31
  const float* mb = mem + ((size_t)b << 17) + v0 + (c4 << 2);
  f32x4 buf[8];
  {
    f32x4 a = {0.f, 0.f, 0.f, 0.f};
#pragma unroll
    for (int i = 0; i < 8; ++i) {
      const int k = (i << 5) + g;
      buf[i] = __builtin_nontemporal_load((const f32x4*)(mb + ((size_t)k << 9)));
      const float s = lwk[k];
      a.x += s * buf[i].x; a.y += s * buf[i].y;
      a.z += s * buf[i].z; a.w += s * buf[i].w;
    }
    part[g][c4] = a;
  }
  __syncthreads();
  if (tid < 64) {
    float vh = 0.f;
#pragma unroll
    for (int gg = 0; gg < 32; ++gg) vh += part[gg][tid >> 2][tid & 3];
    const size_t wvo = (size_t)b * 768 + 256 + v0 + tid;
    const float wv = tanhf(wkvp[wvo] + wkvp[PS + wvo]);
    lerr[tid] = fminf(1.f, fmaxf(-1.f, wv - vh));
  }
  __syncthreads();
  const float et = eta[b], fo = fg[b];
  const float omf = 1.f - fo;
  const bool vb = valid[b] != 0;
  const f32x4 e4 = *(const f32x4*)&lerr[c4 << 2];
  float* ob = outm + ((size_t)b << 17) + v0 + (c4 << 2);
#pragma unroll
  for (int i = 0; i < 8; ++i) {
    const int k = (i << 5) + g;
    const float wke = lwk[k] * et;
    f32x4 r;
    r.x = fminf(10.f, fmaxf(-10.f, omf * buf[i].x + wke * e4.x));
    r.y = fminf(10.f, fmaxf(-10.f, omf * buf[i].y + wke * e4.y));
    r.z = fminf(10.f, fmaxf(-10.f, omf * buf[i].z + wke * e4.z));
    r.w = fminf(10.f, fmaxf(-10.f, omf * buf[i].w + wke * e4.w));
    if (!vb) r = buf[i];
    __builtin_nontemporal_store(r, (f32x4*)(ob + ((size_t)k << 9)));
  }
}

// ---- host -------------------------------------------------------------
extern "C" void kernel_launch(void* const* d_in, const int* in_sizes, int n_in,
                              void* d_out, int out_size, void* d_ws, size_t ws_size,
                              hipStream_t stream) {
  const float* x = (const float*)d_in[0];
  const float* mem = (const float*)d_in[1];
  const unsigned char* valid = (const unsigned char*)d_in[2];
  const float* w_rk = (const float*)d_in[3];
  const float* w_wk = (const float*)d_in[4];
  const float* w_wv = (const float*)d_in[5];
  const float* w_rp = (const float*)d_in[6];
  const float* w_wg = (const float*)d_in[7];
  const float* b_wg = (const float*)d_in[8];
  const float* w_fg = (const float*)d_in[9];
  const float* b_fg = (const float*)d_in[10];
  const float* scale1 = (const float*)d_in[11];
  const float* scale2 = (const float*)d_in[12];
  const float* scale3 = (const float*)d_in[13];
  const float* w_fc1 = (const float*)d_in[14];
  const float* b_fc1 = (const float*)d_in[15];
  const float* w_fc2 = (const float*)d_in[16];
  const float* b_fc2 = (const float*)d_in[17];
  const float* gamma1 = (const float*)d_in[18];
  const float* gamma2 = (const float*)d_in[19];

  char* ws = (char*)d_ws;
  size_t off = 0;
  auto alloc = [&](size_t bytes) -> void* {
    void* p = (void*)(ws + off);
    off = (off + bytes + 255) & ~(size_t)255;
    return p;
  };

  unsigned short* wT_rk = (unsigned short*)alloc((size_t)K_ * H_ * 2);
  unsigned short* wT_wkv = (unsigned short*)alloc((size_t)768 * H_ * 2);
  unsigned short* wT_rp = (unsigned short*)alloc((size_t)H_ * V_ * 2);
  unsigned short* wT_f1 = (unsigned short*)alloc((size_t)F_ * H_ * 2);
  unsigned short* wT_f2 = (unsigned short*)alloc((size_t)H_ * F_ * 2);
  unsigned short* h1 = (unsigned short*)alloc((size_t)B_ * H_ * 2);
  float* rk_pre = (float*)alloc((size_t)4 * B_ * K_ * 4);
  unsigned short* rv = (unsigned short*)alloc((size_t)B_ * V_ * 2);
  float* projp = (float*)alloc((size_t)2 * B_ * H_ * 4);
  float* x1 = (float*)alloc((size_t)B_ * H_ * 4);
  unsigned short* h2 = (unsigned short*)alloc((size_t)B_ * H_ * 2);
  unsigned short* ybf = (unsigned short*)alloc((size_t)B_ * F_ * 2);
  float* fc2p = (float*)alloc((size_t)4 * B_ * H_ * 4);
  unsigned short* w3 = (unsigned short*)alloc((size_t)B_ * H_ * 2);
  float* wkvp = (float*)alloc((size_t)2 * B_ * 768 * 4);
  float* eta = (float*)alloc((size_t)B_ * 4);
  float* fg = (float*)alloc((size_t)B_ * 4);

  float* xout = (float*)d_out;
  float* outm = (float*)d_out + (size_t)B_ * H_;

  // 1. transposes (f32 [R][C] -> bf16 [C][R], 64x64 tiles) + norm1
  TArgs ta;
  int blk = 0;
  auto setj = [&](int i, const float* s, unsigned short* d, int R, int C) {
    ta.j[i] = {s, d, R, C, C / 64, blk};
    blk += (R / 64) * (C / 64);
  };
  setj(0, w_rk, wT_rk, H_, K_);
  setj(1, w_wk, wT_wkv, H_, K_);                    // rows 0..255 of wT_wkv
  setj(2, w_wv, wT_wkv + (size_t)K_ * H_, H_, V_);  // rows 256..767
  setj(3, w_rp, wT_rp, V_, H_);
  setj(4, w_fc1, wT_f1, H_, F_);
  setj(5, w_fc2, wT_f2, F_, H_);
  prep_kernel<<<blk + B_, 256, 0, stream>>>(ta, x, scale1, h1, blk);

  // read path
  gemm2<64, false><<<dim3(K_ / 64, B_ / 64, 4), 256, 0, stream>>>(
      h1, wT_rk, rk_pre, nullptr, nullptr, B_, K_, H_, H_ / 4);
  read_einsum<<<B_ * 2, 512, 0, stream>>>(mem, rk_pre, rv);
  gemm2<64, false><<<dim3(H_ / 64, B_ / 64, 2), 256, 0, stream>>>(
      rv, wT_rp, projp, nullptr, nullptr, B_, H_, V_, V_ / 2);
  add1_norm2<<<B_, 256, 0, stream>>>(x, projp, gamma1, scale2, x1, h2);

  // MLP
  gemm2<128, true><<<dim3(F_ / 128, B_ / 64), 256, 0, stream>>>(
      h2, wT_f1, nullptr, ybf, b_fc1, B_, F_, H_, H_);
  gemm2<128, false><<<dim3(H_ / 128, B_ / 64, 4), 256, 0, stream>>>(
      ybf, wT_f2, fc2p, nullptr, nullptr, B_, H_, F_, F_ / 4);
  add2_norm3<<<B_, 256, 0, stream>>>(x1, fc2p, gamma2, b_fc2, scale3, w_wg, b_wg,
                                     w_fg, b_fg, xout, w3, eta, fg);

  // write path: wk (N 0..255) and wv (N 256..767) in one GEMM, splitK=2
  gemm2<64, false><<<dim3(768 / 64, B_ / 64, 2), 256, 0, stream>>>(
      w3, wT_wkv, wkvp, nullptr, nullptr, B_, 768, H_, H_ / 2);
  write_update<<<B_ * 8, 512, 0, stream>>>(mem, wkvp, eta, fg, valid, outm);
}

// Round 15
// 201.827 us; speedup vs baseline: 1.3342x; 1.3342x over previous
//
#include <hip/hip_runtime.h>
#include <math.h>

// PropagatorBlock: B=512, H=1024, K=256, V=512, MUL=4
constexpr int B_ = 512;
constexpr int H_ = 1024;
constexpr int K_ = 256;
constexpr int V_ = 512;
constexpr int F_ = 4096;  // MUL*H

typedef __attribute__((ext_vector_type(8))) short bf16x8;
typedef __attribute__((ext_vector_type(4))) float f32x4;

#define GLD16(gp, lp)                                                   \
  __builtin_amdgcn_global_load_lds(                                     \
      (const __attribute__((address_space(1))) void*)(gp),              \
      (__attribute__((address_space(3))) void*)(lp), 16, 0, 0)

// ---- helpers ----------------------------------------------------------
static __device__ __forceinline__ unsigned short f2bf(float f) {
  union { float f; unsigned int u; } a; a.f = f;
  unsigned int u = a.u;
  return (unsigned short)((u + 0x7FFFu + ((u >> 16) & 1u)) >> 16);  // RNE
}

static __device__ __forceinline__ float block_sum256(float v, float* sbuf) {
#pragma unroll
  for (int o = 32; o > 0; o >>= 1) v += __shfl_down(v, o, 64);
  const int w = threadIdx.x >> 6;
  __syncthreads();
  if ((threadIdx.x & 63) == 0) sbuf[w] = v;
  __syncthreads();
  return sbuf[0] + sbuf[1] + sbuf[2] + sbuf[3];
}

// 512-thread block sum (8 waves)
static __device__ __forceinline__ float block_sum512(float v, float* sbuf) {
#pragma unroll
  for (int o = 32; o > 0; o >>= 1) v += __shfl_down(v, o, 64);
  const int w = threadIdx.x >> 6;
  __syncthreads();
  if ((threadIdx.x & 63) == 0) sbuf[w] = v;
  __syncthreads();
  float s = 0.f;
#pragma unroll
  for (int i = 0; i < 8; ++i) s += sbuf[i];
  return s;
}

// ---- prep v2: all 6 weight transposes (64x64 tiles) + norm1 -----------
struct TJob { const float* src; unsigned short* dst; int R, C, cb, blk0; };
struct TArgs { TJob j[6]; };

__global__ __launch_bounds__(256) void prep_kernel(
    TArgs args, const float* __restrict__ x, const float* __restrict__ scale,
    unsigned short* __restrict__ h1, int tblocks) {
  __shared__ unsigned short t16[64][68];
  __shared__ float sbuf[4];
  const int id = blockIdx.x;
  const int tid = threadIdx.x;
  if (id >= tblocks) {
    const int b = id - tblocks;
    const float* xr = x + ((size_t)b << 10);
    float loc[4]; float ss = 0.f;
#pragma unroll
    for (int it = 0; it < 4; ++it) { float v = xr[(it << 8) + tid]; loc[it] = v; ss += v * v; }
    ss = block_sum256(ss, sbuf);
    const float r = rsqrtf(ss * (1.f / 1024.f) + 1e-6f);
    unsigned short* orow = h1 + ((size_t)b << 10);
#pragma unroll
    for (int it = 0; it < 4; ++it) { const int j = (it << 8) + tid; orow[j] = f2bf(loc[it] * r * scale[j]); }
    return;
  }
  int ji = 0;
#pragma unroll
  for (int i = 1; i < 6; ++i) if (id >= args.j[i].blk0) ji = i;
  const TJob J = args.j[ji];
  const int lb = id - J.blk0;
  const int bx = lb % J.cb, by = lb / J.cb;
  const int c0 = bx << 6, r0 = by << 6;
  const int lr = tid >> 4, lc = (tid & 15) << 2;
#pragma unroll
  for (int i = 0; i < 4; ++i) {
    const int row = (i << 4) + lr;
    const f32x4 v = *(const f32x4*)&J.src[(size_t)(r0 + row) * J.C + c0 + lc];
    ushort4 u;
    u.x = f2bf(v.x); u.y = f2bf(v.y); u.z = f2bf(v.z); u.w = f2bf(v.w);
    *(ushort4*)&t16[row][lc] = u;
  }
  __syncthreads();
  const int oc = tid >> 5, j = tid & 31;
#pragma unroll
  for (int i = 0; i < 8; ++i) {
    const int c = (i << 3) + oc;
    const unsigned lo = t16[2 * j][c], hi = t16[2 * j + 1][c];
    *(unsigned*)&J.dst[(size_t)(c0 + c) * J.R + r0 + 2 * j] = lo | (hi << 16);
  }
}

// ---- GEMM: C[M][N] (+z partials) = A[M][K] * BT[N][K]^T ---------------
// 2-phase dbuf + counted vmcnt (tile t+1 loads stay in flight).
template <int BN, bool SILU>
__global__ __launch_bounds__(256) void gemm2(
    const unsigned short* __restrict__ A, const unsigned short* __restrict__ BT,
    float* __restrict__ Cf, unsigned short* __restrict__ Cb,
    const float* __restrict__ bias, int M, int N, int K, int Ksub) {
  __shared__ unsigned short lsa[2][64 * 64];
  __shared__ unsigned short lsb[2][BN * 64];
  const int tid = threadIdx.x;
  const int m0 = blockIdx.y << 6, n0 = blockIdx.x * BN;
  const int kbeg = blockIdx.z * Ksub;
  const int w = tid >> 6, l = tid & 63;
  const int l15 = l & 15, lg = l >> 4;
  const int wm = (w >> 1) * 32, wn = (w & 1) * (BN / 2);
  constexpr int NF = BN / 32;
  f32x4 acc[2][NF] = {};

  const int sr = l >> 3;
  const int sc = ((l & 7) ^ sr) * 8;
  const int srow = w * 8 + sr;
  const unsigned short* ga0 = A + (size_t)(m0 + srow) * K + sc;
  const unsigned short* gb0 = BT + (size_t)(n0 + srow) * K + sc;
  const int rx = l15 & 7;

  auto STAGE = [&](int buf, int k0) {
#pragma unroll
    for (int c = 0; c < 2; ++c)
      GLD16(ga0 + (size_t)(c * 32) * K + k0, &lsa[buf][c * 2048 + w * 512]);
#pragma unroll
    for (int c = 0; c < NF; ++c)
      GLD16(gb0 + (size_t)(c * 32) * K + k0, &lsb[buf][c * 2048 + w * 512]);
  };

  const int nt = Ksub >> 6;
  STAGE(0, kbeg);
  __builtin_amdgcn_sched_barrier(0);
  int cur = 0;
  for (int t = 0; t < nt; ++t) {
    if (t + 1 < nt) {
      STAGE(cur ^ 1, kbeg + ((t + 1) << 6));
      __builtin_amdgcn_sched_barrier(0);
      if constexpr (NF == 2) {
        asm volatile("s_waitcnt vmcnt(4)" ::: "memory");
      } else {
        asm volatile("s_waitcnt vmcnt(6)" ::: "memory");
      }
    } else {
      asm volatile("s_waitcnt vmcnt(0)" ::: "memory");
    }
    __builtin_amdgcn_sched_barrier(0);
    __builtin_amdgcn_s_barrier();
    __builtin_amdgcn_sched_barrier(0);
    const unsigned short* la = lsa[cur];
    const unsigned short* lb = lsb[cur];
    bf16x8 af[2][2], bv[2][NF];
#pragma unroll
    for (int kh = 0; kh < 2; ++kh) {
      const int ch = ((kh * 4 + lg) ^ rx) * 8;
#pragma unroll
      for (int mf = 0; mf < 2; ++mf)
        af[kh][mf] = *(const bf16x8*)&la[(wm + mf * 16 + l15) * 64 + ch];
#pragma unroll
      for (int nf = 0; nf < NF; ++nf)
        bv[kh][nf] = *(const bf16x8*)&lb[(wn + nf * 16 + l15) * 64 + ch];
    }
#pragma unroll
    for (int kh = 0; kh < 2; ++kh)
#pragma unroll
      for (int mf = 0; mf < 2; ++mf)
#pragma unroll
        for (int nf = 0; nf < NF; ++nf)
          acc[mf][nf] = __builtin_amdgcn_mfma_f32_16x16x32_bf16(
              af[kh][mf], bv[kh][nf], acc[mf][nf], 0, 0, 0);
    asm volatile("s_waitcnt lgkmcnt(0)" ::: "memory");
    __builtin_amdgcn_sched_barrier(0);
    __builtin_amdgcn_s_barrier();
    __builtin_amdgcn_sched_barrier(0);
    cur ^= 1;
  }

  if constexpr (SILU) {
#pragma unroll
    for (int mf = 0; mf < 2; ++mf)
#pragma unroll
      for (int nf = 0; nf < NF; ++nf) {
        const int col = n0 + wn + nf * 16 + l15;
        const float bi = bias[col];
#pragma unroll
        for (int i = 0; i < 4; ++i) {
          const int row = m0 + wm + mf * 16 + (lg << 2) + i;
          const float z = acc[mf][nf][i] + bi;
          Cb[(size_t)row * N + col] = f2bf(z / (1.f + expf(-z)));
        }
      }
  } else {
    float* Cz = Cf + (size_t)blockIdx.z * M * N;
#pragma unroll
    for (int mf = 0; mf < 2; ++mf)
#pragma unroll
      for (int nf = 0; nf < NF; ++nf) {
        const int r = m0 + wm + mf * 16 + (lg << 2);
        const int c = n0 + wn + nf * 16 + l15;
        float* cp = Cz + (size_t)r * N + c;
#pragma unroll
        for (int i = 0; i < 4; ++i) cp[(size_t)i * N] = acc[mf][nf][i];
      }
  }
}

// ---- einsum (R9 version): 512 thr / 8 waves, block=(b, v-half) --------
__global__ __launch_bounds__(512) void read_einsum(
    const float* __restrict__ mem, const float* __restrict__ rk_pre,
    unsigned short* __restrict__ rv) {
  __shared__ float sbuf[8];
  __shared__ float lrk[256];
  __shared__ float part[8][256];
  const int tid = threadIdx.x;
  const int b = blockIdx.x >> 1;
  const int v0 = (blockIdx.x & 1) << 8;  // 256 cols per block
  {
    constexpr size_t PS = (size_t)B_ * K_;
    float v = 0.f;
    if (tid < 256) {
#pragma unroll
      for (int z = 0; z < 4; ++z) v += rk_pre[z * PS + ((size_t)b << 8) + tid];
    }
    const float ss = block_sum512(v * v, sbuf);
    if (tid < 256) lrk[tid] = v * rsqrtf(ss * (1.f / 256.f) + 1e-6f) * 0.0625f;
  }
  __syncthreads();
  const int w = tid >> 6, l = tid & 63;
  const float* base = mem + ((size_t)b << 17) + v0 + (l << 2);
  f32x4 a = {0.f, 0.f, 0.f, 0.f};
#pragma unroll 8
  for (int kk = 0; kk < 32; ++kk) {
    const int k = (w << 5) + kk;
    const f32x4 m4 = *(const f32x4*)(base + ((size_t)k << 9));
    const float s = lrk[k];
    a.x += s * m4.x; a.y += s * m4.y; a.z += s * m4.z; a.w += s * m4.w;
  }
  *(f32x4*)&part[w][l << 2] = a;
  __syncthreads();
  if (tid < 256) {
    float s = 0.f;
#pragma unroll
    for (int g = 0; g < 8; ++g) s += part[g][tid];
    rv[((size_t)b << 9) + v0 + tid] = f2bf(s);
  }
}

// ---- x1 = x + gamma1*sum_z proj; h2 = bf16(rmsnorm(x1)*scale2) --------
__global__ __launch_bounds__(256) void add1_norm2(
    const float* __restrict__ x, const float* __restrict__ proj,
    const float* __restrict__ gamma1, const float* __restrict__ scale2,
    float* __restrict__ x1, unsigned short* __restrict__ h2) {
  __shared__ float sbuf[4];
  const int b = blockIdx.x, tid = threadIdx.x;
  const size_t ro = (size_t)b << 10;
  constexpr size_t PS = (size_t)B_ * H_;
  float loc[4]; float ss = 0.f;
#pragma unroll
  for (int it = 0; it < 4; ++it) {
    const int j = (it << 8) + tid;
    const float v = x[ro + j] + gamma1[j] * (proj[ro + j] + proj[PS + ro + j]);
    x1[ro + j] = v; loc[it] = v; ss += v * v;
  }
  ss = block_sum256(ss, sbuf);
  const float r = rsqrtf(ss * (1.f / 1024.f) + 1e-6f);
#pragma unroll
  for (int it = 0; it < 4; ++it) { const int j = (it << 8) + tid; h2[ro + j] = f2bf(loc[it] * r * scale2[j]); }
}

// ---- x2 = x1 + gamma2*(sum_z fc2p[z]+b2); w3; eta; forget -------------
__global__ __launch_bounds__(256) void add2_norm3(
    const float* __restrict__ x1, const float* __restrict__ fc2p,
    const float* __restrict__ gamma2, const float* __restrict__ bias2,
    const float* __restrict__ scale3, const float* __restrict__ wgate,
    const float* __restrict__ bgate, const float* __restrict__ wforget,
    const float* __restrict__ bforget, float* __restrict__ xout,
    unsigned short* __restrict__ w3, float* __restrict__ eta, float* __restrict__ fg) {
  __shared__ float sbuf[4];
  const int b = blockIdx.x, tid = threadIdx.x;
  const size_t ro = (size_t)b << 10;
  constexpr size_t PS = (size_t)B_ * H_;
  float loc[4]; float ss = 0.f;
#pragma unroll
  for (int it = 0; it < 4; ++it) {
    const int j = (it << 8) + tid;
    float acc = bias2[j];
#pragma unroll
    for (int z = 0; z < 4; ++z) acc += fc2p[z * PS + ro + j];
    const float v = x1[ro + j] + gamma2[j] * acc;
    xout[ro + j] = v; loc[it] = v; ss += v * v;
  }
  ss = block_sum256(ss, sbuf);
  const float r = rsqrtf(ss * (1.f / 1024.f) + 1e-6f);
  float dg = 0.f, df = 0.f;
#pragma unroll
  for (int it = 0; it < 4; ++it) {
    const int j = (it << 8) + tid;
    const float w = loc[it] * r * scale3[j];
    w3[ro + j] = f2bf(w);
    dg += w * wgate[j]; df += w * wforget[j];
  }
  dg = block_sum256(dg, sbuf);
  df = block_sum256(df, sbuf);
  if (tid == 0) {
    eta[b] = 0.1f / (1.f + expf(-(dg + bgate[0])));
    fg[b] = 0.02f / (1.f + expf(-(df + bforget[0])));
  }
}

// ---- write_update (R13 version + NT phase-1 loads) --------------------
// block = (b, v-quarter 128 cols). Thread owns 16 f32x4 of the slab in
// registers: phase1 NT-load+dot, phase2 err, phase3 update from regs +
// NT store. No re-read; mem dead after phase 1 -> NT loads.
__global__ __launch_bounds__(512, 4) void write_update(
    const float* __restrict__ mem, const float* __restrict__ wkvp,
    const float* __restrict__ eta, const float* __restrict__ fg,
    const unsigned char* __restrict__ valid, float* __restrict__ outm) {
  __shared__ float sbuf[8];
  __shared__ float lwk[256];
  __shared__ f32x4 part[16][32];
  __shared__ float lerr[128];
  const int tid = threadIdx.x;
  const int b = blockIdx.x >> 2;
  const int v0 = (blockIdx.x & 3) << 7;  // 128 cols per block
  constexpr size_t PS = (size_t)B_ * 768;
  {
    float v = 0.f;
    if (tid < 256) v = wkvp[(size_t)b * 768 + tid] + wkvp[PS + (size_t)b * 768 + tid];
    const float ss = block_sum512(v * v, sbuf);
    if (tid < 256) lwk[tid] = v * rsqrtf(ss * (1.f / 256.f) + 1e-6f) * 0.0625f;
  }
  __syncthreads();
  const int w = tid >> 6, l = tid & 63;
  const int g = (w << 1) + (l >> 5);  // row-group 0..15
  const int c4 = l & 31;              // col quad (4 floats)
  const float* mb = mem + ((size_t)b << 17) + v0 + (c4 << 2);
  f32x4 buf[16];
  {
    f32x4 a = {0.f, 0.f, 0.f, 0.f};
#pragma unroll
    for (int i = 0; i < 16; ++i) {
      const int k = (i << 4) + g;
      buf[i] = __builtin_nontemporal_load((const f32x4*)(mb + ((size_t)k << 9)));
      const float s = lwk[k];
      a.x += s * buf[i].x; a.y += s * buf[i].y;
      a.z += s * buf[i].z; a.w += s * buf[i].w;
    }
    part[g][c4] = a;
  }
  __syncthreads();
  if (tid < 128) {
    float vh = 0.f;
#pragma unroll
    for (int gg = 0; gg < 16; ++gg) vh += part[gg][tid >> 2][tid & 3];
    const size_t wvo = (size_t)b * 768 + 256 + v0 + tid;
    const float wv = tanhf(wkvp[wvo] + wkvp[PS + wvo]);
    lerr[tid] = fminf(1.f, fmaxf(-1.f, wv - vh));
  }
  __syncthreads();
  const float et = eta[b], fo = fg[b];
  const float omf = 1.f - fo;
  const bool vb = valid[b] != 0;
  const f32x4 e4 = *(const f32x4*)&lerr[c4 << 2];
  float* ob = outm + ((size_t)b << 17) + v0 + (c4 << 2);
#pragma unroll
  for (int i = 0; i < 16; ++i) {
    const int k = (i << 4) + g;
    const float wke = lwk[k] * et;
    f32x4 r;
    r.x = fminf(10.f, fmaxf(-10.f, omf * buf[i].x + wke * e4.x));
    r.y = fminf(10.f, fmaxf(-10.f, omf * buf[i].y + wke * e4.y));
    r.z = fminf(10.f, fmaxf(-10.f, omf * buf[i].z + wke * e4.z));
    r.w = fminf(10.f, fmaxf(-10.f, omf * buf[i].w + wke * e4.w));
    if (!vb) r = buf[i];
    __builtin_nontemporal_store(r, (f32x4*)(ob + ((size_t)k << 9)));
  }
}

// ---- host -------------------------------------------------------------
extern "C" void kernel_launch(void* const* d_in, const int* in_sizes, int n_in,
                              void* d_out, int out_size, void* d_ws, size_t ws_size,
                              hipStream_t stream) {
  const float* x = (const float*)d_in[0];
  const float* mem = (const float*)d_in[1];
  const unsigned char* valid = (const unsigned char*)d_in[2];
  const float* w_rk = (const float*)d_in[3];
  const float* w_wk = (const float*)d_in[4];
  const float* w_wv = (const float*)d_in[5];
  const float* w_rp = (const float*)d_in[6];
  const float* w_wg = (const float*)d_in[7];
  const float* b_wg = (const float*)d_in[8];
  const float* w_fg = (const float*)d_in[9];
  const float* b_fg = (const float*)d_in[10];
  const float* scale1 = (const float*)d_in[11];
  const float* scale2 = (const float*)d_in[12];
  const float* scale3 = (const float*)d_in[13];
  const float* w_fc1 = (const float*)d_in[14];
  const float* b_fc1 = (const float*)d_in[15];
  const float* w_fc2 = (const float*)d_in[16];
  const float* b_fc2 = (const float*)d_in[17];
  const float* gamma1 = (const float*)d_in[18];
  const float* gamma2 = (const float*)d_in[19];

  char* ws = (char*)d_ws;
  size_t off = 0;
  auto alloc = [&](size_t bytes) -> void* {
    void* p = (void*)(ws + off);
    off = (off + bytes + 255) & ~(size_t)255;
    return p;
  };

  unsigned short* wT_rk = (unsigned short*)alloc((size_t)K_ * H_ * 2);
  unsigned short* wT_wkv = (unsigned short*)alloc((size_t)768 * H_ * 2);
  unsigned short* wT_rp = (unsigned short*)alloc((size_t)H_ * V_ * 2);
  unsigned short* wT_f1 = (unsigned short*)alloc((size_t)F_ * H_ * 2);
  unsigned short* wT_f2 = (unsigned short*)alloc((size_t)H_ * F_ * 2);
  unsigned short* h1 = (unsigned short*)alloc((size_t)B_ * H_ * 2);
  float* rk_pre = (float*)alloc((size_t)4 * B_ * K_ * 4);
  unsigned short* rv = (unsigned short*)alloc((size_t)B_ * V_ * 2);
  float* projp = (float*)alloc((size_t)2 * B_ * H_ * 4);
  float* x1 = (float*)alloc((size_t)B_ * H_ * 4);
  unsigned short* h2 = (unsigned short*)alloc((size_t)B_ * H_ * 2);
  unsigned short* ybf = (unsigned short*)alloc((size_t)B_ * F_ * 2);
  float* fc2p = (float*)alloc((size_t)4 * B_ * H_ * 4);
  unsigned short* w3 = (unsigned short*)alloc((size_t)B_ * H_ * 2);
  float* wkvp = (float*)alloc((size_t)2 * B_ * 768 * 4);
  float* eta = (float*)alloc((size_t)B_ * 4);
  float* fg = (float*)alloc((size_t)B_ * 4);

  float* xout = (float*)d_out;
  float* outm = (float*)d_out + (size_t)B_ * H_;

  // 1. transposes (f32 [R][C] -> bf16 [C][R], 64x64 tiles) + norm1
  TArgs ta;
  int blk = 0;
  auto setj = [&](int i, const float* s, unsigned short* d, int R, int C) {
    ta.j[i] = {s, d, R, C, C / 64, blk};
    blk += (R / 64) * (C / 64);
  };
  setj(0, w_rk, wT_rk, H_, K_);
  setj(1, w_wk, wT_wkv, H_, K_);                    // rows 0..255 of wT_wkv
  setj(2, w_wv, wT_wkv + (size_t)K_ * H_, H_, V_);  // rows 256..767
  setj(3, w_rp, wT_rp, V_, H_);
  setj(4, w_fc1, wT_f1, H_, F_);
  setj(5, w_fc2, wT_f2, F_, H_);
  prep_kernel<<<blk + B_, 256, 0, stream>>>(ta, x, scale1, h1, blk);

  // read path
  gemm2<64, false><<<dim3(K_ / 64, B_ / 64, 4), 256, 0, stream>>>(
      h1, wT_rk, rk_pre, nullptr, nullptr, B_, K_, H_, H_ / 4);
  read_einsum<<<B_ * 2, 512, 0, stream>>>(mem, rk_pre, rv);
  gemm2<64, false><<<dim3(H_ / 64, B_ / 64, 2), 256, 0, stream>>>(
      rv, wT_rp, projp, nullptr, nullptr, B_, H_, V_, V_ / 2);
  add1_norm2<<<B_, 256, 0, stream>>>(x, projp, gamma1, scale2, x1, h2);

  // MLP
  gemm2<128, true><<<dim3(F_ / 128, B_ / 64), 256, 0, stream>>>(
      h2, wT_f1, nullptr, ybf, b_fc1, B_, F_, H_, H_);
  gemm2<128, false><<<dim3(H_ / 128, B_ / 64, 4), 256, 0, stream>>>(
      ybf, wT_f2, fc2p, nullptr, nullptr, B_, H_, F_, F_ / 4);
  add2_norm3<<<B_, 256, 0, stream>>>(x1, fc2p, gamma2, b_fc2, scale3, w_wg, b_wg,
                                     w_fg, b_fg, xout, w3, eta, fg);

  // write path: wk (N 0..255) and wv (N 256..767) in one GEMM, splitK=2
  gemm2<64, false><<<dim3(768 / 64, B_ / 64, 2), 256, 0, stream>>>(
      w3, wT_wkv, wkvp, nullptr, nullptr, B_, 768, H_, H_ / 2);
  write_update<<<B_ * 4, 512, 0, stream>>>(mem, wkvp, eta, fg, valid, outm);
}